// Round 7
// baseline (206.306 us; speedup 1.0000x reference)
//
#include <hip/hip_runtime.h>
#include <math.h>

// Problem constants
#define NPIX   131072      // 32 * 64 * 64 pixels
#define KCODES 512
#define DDIM   64
#define HWSZ   4096        // 64*64
#define NELEM  8388608     // NPIX * DDIM

// d_out layout (fp32): [0]=loss, [1..1+NELEM)=q_nchw, [1+NELEM]=perplexity,
// [2+NELEM .. 2+2*NELEM)=q_nhwc flat
#define OUT_NCHW_OFF 1
#define OUT_PERP_IDX (1 + NELEM)
#define OUT_NHWC_OFF (2 + NELEM)

// ws layout (fp32 words): [0]=loss, [16..528)=|e|^2, [544..1056)=counts(uint),
// [1056]=done counter, [2048..)=e bf16 hi/lo B-fragments (128KB)
#define WS_NRM_OFF  16
#define WS_CNT_OFF  544
#define WS_FRAG_F32 2048

typedef __bf16 bf16x8 __attribute__((ext_vector_type(8)));
typedef float  f32x4  __attribute__((ext_vector_type(4)));

// Prep (verified R5/R6): B-fragment pack + |e|^2 (bit-identical fmaf chain) +
// zero loss/counts/done. ws is re-poisoned every call.
__global__ __launch_bounds__(256) void vq_prep(const float* __restrict__ emb,
                                               float* __restrict__ ws) {
    int tid  = blockIdx.x * 256 + threadIdx.x;   // 0..8191
    int lane = tid & 63;
    int h    = (tid >> 6) & 1;
    int ks   = (tid >> 7) & 1;
    int ct   = tid >> 8;                         // == blockIdx.x (0..31)
    int code = ct * 16 + (lane & 15);
    int d0   = ks * 32 + ((lane >> 4) & 3) * 8;
    const float* src = emb + code * DDIM + d0;
    unsigned short us[8];
#pragma unroll
    for (int j = 0; j < 8; ++j) {
        float f = src[j];
        __bf16 hb = (__bf16)f;                   // RTN
        if (h == 0) {
            us[j] = __builtin_bit_cast(unsigned short, hb);
        } else {
            __bf16 lb = (__bf16)(f - (float)hb);
            us[j] = __builtin_bit_cast(unsigned short, lb);
        }
    }
    uint4 v;
    v.x = us[0] | ((unsigned)us[1] << 16);
    v.y = us[2] | ((unsigned)us[3] << 16);
    v.z = us[4] | ((unsigned)us[5] << 16);
    v.w = us[6] | ((unsigned)us[7] << 16);
    reinterpret_cast<uint4*>(ws + WS_FRAG_F32)[tid] = v;

    if (threadIdx.x < 16) {
        int c = ct * 16 + threadIdx.x;
        const float4* e4 = reinterpret_cast<const float4*>(emb + c * DDIM);
        float s = 0.f;
#pragma unroll
        for (int i = 0; i < 16; ++i) {
            float4 w = e4[i];
            s = fmaf(w.x, w.x, s); s = fmaf(w.y, w.y, s);
            s = fmaf(w.z, w.z, s); s = fmaf(w.w, w.w, s);
        }
        ws[WS_NRM_OFF + c] = s;
    }
    if (blockIdx.x == 0) {
        unsigned* g = reinterpret_cast<unsigned*>(ws);
        g[WS_CNT_OFF + threadIdx.x] = 0u;
        g[WS_CNT_OFF + threadIdx.x + 256] = 0u;
        if (threadIdx.x == 0) { ws[0] = 0.f; g[WS_CNT_OFF + 512] = 0u; }
    }
}

// R7: no 64KB x-staging tile (LDS 76->23KB => ~5 blocks/CU instead of 2 for
// latency hiding). A-frags built directly from global (R5-verified layout);
// |x|^2 via quarter-lane shuffle (R5-verified). Device fence + finalize moved
// AFTER the epilogue (R6's mid-kernel fence invalidated caches ahead of the
// epilogue gathers: 56 -> 95us). K-loop/argmin/epilogue identical to R4/R6.
__global__ __launch_bounds__(256, 2) void vq_main(const float* __restrict__ in,
                                                  const float* __restrict__ emb,
                                                  float* __restrict__ out,
                                                  float* __restrict__ ws) {
    __shared__ float    q_lds[64 * 65];
    __shared__ float    nrm_lds[KCODES];
    __shared__ float    x2_lds[256];
    __shared__ int      idx_lds[256];
    __shared__ unsigned cnt_lds[KCODES];
    __shared__ float    red_tot;
    __shared__ unsigned last_flag;
    __shared__ double   rd[4];

    const int t = threadIdx.x;
    const int l = t & 63, wid = t >> 6;          // wave owns pixels [wid*64, +64)
    cnt_lds[t] = 0u; cnt_lds[t + 256] = 0u;
    nrm_lds[t]       = ws[WS_NRM_OFF + t];
    nrm_lds[t + 256] = ws[WS_NRM_OFF + t + 256];
    if (t == 0) { red_tot = 0.f; last_flag = 0u; }

    const int pix0 = blockIdx.x << 8;
    const int b    = pix0 >> 12;
    const int hwb  = pix0 & (HWSZ - 1);
    const float* inb = in + (size_t)b * (DDIM * HWSZ) + hwb;

    // A-fragments (A[m][k]: m=lane&15, k=(lane>>4)*8+j) straight from global:
    // per j the wave reads 4 d-rows x 16 consecutive pixels (64B segments,
    // each element read exactly once per block). hi/lo bf16 split.
    const int q = l >> 4;                        // 0..3 (k-quarter)
    bf16x8 a_hi[4][2], a_lo[4][2];
    float x2p[4];
#pragma unroll
    for (int pt = 0; pt < 4; ++pt) {
        const float* px = inb + wid * 64 + pt * 16 + (l & 15);
        float x2 = 0.f;
#pragma unroll
        for (int ks = 0; ks < 2; ++ks) {
            const int d0 = ks * 32 + q * 8;
            float fv[8];
#pragma unroll
            for (int j = 0; j < 8; ++j) fv[j] = px[(size_t)(d0 + j) * HWSZ];
            bf16x8 h8, l8;
#pragma unroll
            for (int j = 0; j < 8; ++j) {
                __bf16 hb = (__bf16)fv[j];
                h8[j] = hb;
                l8[j] = (__bf16)(fv[j] - (float)hb);
                x2 = fmaf(fv[j], fv[j], x2);
            }
            a_hi[pt][ks] = h8; a_lo[pt][ks] = l8;
        }
        x2p[pt] = x2;
    }
#pragma unroll
    for (int pt = 0; pt < 4; ++pt) {             // sum the 4 k-quarters
        x2p[pt] += __shfl_xor(x2p[pt], 16, 64);
        x2p[pt] += __shfl_xor(x2p[pt], 32, 64);
    }
    if (l < 16) {                                // lanes 0..15 hold pixel totals
#pragma unroll
        for (int pt = 0; pt < 4; ++pt) x2_lds[wid * 64 + pt * 16 + l] = x2p[pt];
    }

    const uint4* fragp = reinterpret_cast<const uint4*>(ws + WS_FRAG_F32);
    float best[4][4]; int bidx[4][4];
#pragma unroll
    for (int pt = 0; pt < 4; ++pt)
#pragma unroll
    for (int r = 0; r < 4; ++r) { best[pt][r] = 3.4e38f; bidx[pt][r] = 0; }

    // B-frag double buffer: 8 frags/chunk = [ct][ks][h]
    uint4 bcur[8], bnxt[8];
#pragma unroll
    for (int i = 0; i < 8; ++i) {
        int ct = i >> 2, ks = (i >> 1) & 1, h = i & 1;
        bcur[i] = fragp[(((ct) * 2 + ks) * 2 + h) * 64 + l];
    }
    __syncthreads();                             // nrm/cnt/x2 ready

    for (int cb = 0; cb < KCODES; cb += 32) {
        int ctb = cb >> 4;
        if (cb + 32 < KCODES) {
#pragma unroll
            for (int i = 0; i < 8; ++i) {
                int ct = i >> 2, ks = (i >> 1) & 1, h = i & 1;
                bnxt[i] = fragp[(((ctb + 2 + ct) * 2 + ks) * 2 + h) * 64 + l];
            }
        }
        f32x4 acc[4][2];
#pragma unroll
        for (int pt = 0; pt < 4; ++pt)
#pragma unroll
        for (int ct = 0; ct < 2; ++ct) {
            f32x4 a = {0.f, 0.f, 0.f, 0.f};
#pragma unroll
            for (int ks = 0; ks < 2; ++ks) {
                bf16x8 bh = __builtin_bit_cast(bf16x8, bcur[ct * 4 + ks * 2 + 0]);
                bf16x8 bl = __builtin_bit_cast(bf16x8, bcur[ct * 4 + ks * 2 + 1]);
                a = __builtin_amdgcn_mfma_f32_16x16x32_bf16(a_hi[pt][ks], bh, a, 0, 0, 0);
                a = __builtin_amdgcn_mfma_f32_16x16x32_bf16(a_hi[pt][ks], bl, a, 0, 0, 0);
                a = __builtin_amdgcn_mfma_f32_16x16x32_bf16(a_lo[pt][ks], bh, a, 0, 0, 0);
                a = __builtin_amdgcn_mfma_f32_16x16x32_bf16(a_lo[pt][ks], bl, a, 0, 0, 0);
            }
            acc[pt][ct] = a;
        }
        // argmin update; C/D: col(code)=lane&15, row(pix)=(lane>>4)*4+reg
#pragma unroll
        for (int ct = 0; ct < 2; ++ct) {
            int code = cb + ct * 16 + (l & 15);
            float nv = nrm_lds[code];
#pragma unroll
            for (int pt = 0; pt < 4; ++pt)
#pragma unroll
            for (int r = 0; r < 4; ++r) {
                float d = fmaf(-2.f, acc[pt][ct][r], nv);
                if (d < best[pt][r]) { best[pt][r] = d; bidx[pt][r] = code; }
            }
        }
#pragma unroll
        for (int i = 0; i < 8; ++i) bcur[i] = bnxt[i];
    }

    // Cross-lane argmin across the 16 code columns; (dist, idx) = first-min.
#pragma unroll
    for (int off = 1; off < 16; off <<= 1) {
#pragma unroll
        for (int pt = 0; pt < 4; ++pt)
#pragma unroll
        for (int r = 0; r < 4; ++r) {
            float ob = __shfl_xor(best[pt][r], off, 64);
            int   oi = __shfl_xor(bidx[pt][r], off, 64);
            bool take = (ob < best[pt][r]) || (ob == best[pt][r] && oi < bidx[pt][r]);
            if (take) { best[pt][r] = ob; bidx[pt][r] = oi; }
        }
    }
    if ((l & 15) == 0) {
        float lp = 0.f;
#pragma unroll
        for (int pt = 0; pt < 4; ++pt)
#pragma unroll
        for (int r = 0; r < 4; ++r) {
            int pixl = wid * 64 + pt * 16 + q * 4 + r;
            idx_lds[pixl] = bidx[pt][r];
            atomicAdd(&cnt_lds[bidx[pt][r]], 1u);
            lp += x2_lds[pixl] + best[pt][r];    // |x-e|^2 = x^2 + (|e|^2 - 2x.e)
        }
        atomicAdd(&red_tot, lp);
    }
    __syncthreads();

    if (t == 0) atomicAdd(ws, red_tot);
    unsigned* gcnt = reinterpret_cast<unsigned*>(ws) + WS_CNT_OFF;
    atomicAdd(gcnt + t, cnt_lds[t]);
    atomicAdd(gcnt + t + 256, cnt_lds[t + 256]);

    // Epilogue (proven R3/R4): padded LDS tile -> both layouts coalesced.
    float* out2 = out + OUT_NCHW_OFF;
    float* out3 = out + OUT_NHWC_OFF;
    const float2* emb2 = reinterpret_cast<const float2*>(emb);
    float2* out3_2 = reinterpret_cast<float2*>(out3);

    for (int s = 0; s < 4; ++s) {
#pragma unroll
        for (int it = 0; it < 8; ++it) {
            int fid = it * 256 + t;
            int pp  = fid >> 5;
            int c2  = fid & 31;
            int row = idx_lds[s * 64 + pp];
            float2 v = emb2[row * 32 + c2];
            out3_2[(size_t)(pix0 + s * 64 + pp) * 32 + c2] = v;
            q_lds[pp * 65 + c2 * 2 + 0] = v.x;
            q_lds[pp * 65 + c2 * 2 + 1] = v.y;
        }
        __syncthreads();
#pragma unroll
        for (int it = 0; it < 16; ++it) {
            int did = it * 256 + t;
            int c   = did >> 6;
            int hwl = did & 63;
            out2[(size_t)(b * DDIM + c) * HWSZ + hwb + s * 64 + hwl] = q_lds[hwl * 65 + c];
        }
        __syncthreads();
    }

    // Last-block-done finalize at the TAIL (fence can no longer hurt the
    // epilogue; counts drained by the pre-epilogue barriers' vmcnt(0)).
    __threadfence();
    if (t == 0) {
        unsigned old = atomicAdd(gcnt + 512, 1u);
        last_flag = (old == 511u) ? 1u : 0u;
    }
    __syncthreads();
    if (last_flag) {                             // block-uniform branch
        __threadfence();
        double s = 0.0;
#pragma unroll
        for (int k = t; k < KCODES; k += 256) {
            unsigned c = atomicAdd(gcnt + k, 0u);   // device-scope read
            double p = (double)c / (double)NPIX;
            s += p * log(p + 1e-10);
        }
#pragma unroll
        for (int o = 32; o > 0; o >>= 1) s += __shfl_xor(s, o, 64);
        if ((t & 63) == 0) rd[t >> 6] = s;
        __syncthreads();
        if (t == 0) {
            double tot = rd[0] + rd[1] + rd[2] + rd[3];
            out[OUT_PERP_IDX] = (float)exp(-tot);
            float lv = atomicAdd(ws, 0.f);       // read loss accumulator
            out[0] = 0.25f * lv / (float)NELEM;
        }
    }
}

extern "C" void kernel_launch(void* const* d_in, const int* in_sizes, int n_in,
                              void* d_out, int out_size, void* d_ws, size_t ws_size,
                              hipStream_t stream) {
    const float* in  = (const float*)d_in[0];
    const float* emb = (const float*)d_in[1];
    float* out = (float*)d_out;
    float* ws  = (float*)d_ws;

    vq_prep<<<32, 256, 0, stream>>>(emb, ws);
    vq_main<<<NPIX / 256, 256, 0, stream>>>(in, emb, out, ws);
}